// Round 9
// baseline (19126.012 us; speedup 1.0000x reference)
//
#include <hip/hip_runtime.h>

// BiLSTM-CRF tagger. V=100000 E=300 H=512 C=40 T=4096. ALL I/O float32.
// r15 = r14 (proven 16.42ms pass) + two changes:
//   (a) lstm poll width 32B -> 64B, 31 pollers (was 62). A 64B chunk is
//       exactly ONE producer block's coalesced 16-lane store (the natural
//       arrival unit). Halves MALL request rate (3968->1984 concurrent
//       system-scope pollers); fewer arrival cohorts -> fewer stacked RTs in
//       the divergent poll loop (the 2.4x gap between the 1700cy model and
//       the 4170cy measured step). Same per-word predicate, same append-only
//       addresses, same sc0sc1 ops, producer store untouched.
//   (b) vit_fwd_k: LDS round-trip -> __shfl broadcast of s(t-1); fmax tree
//       unchanged (bit-exact: same candidates, max is order-independent).
// r11/r13 lesson: pipelined reg-destination polling pays an ~RT drain at exit;
//   r6-style load+vmcnt(0)+check is the only safe poll shape.
// r10 lesson: append-only polled addresses + sc0sc1 (MALL) ops only.
// Sync scheme (r4..r9, proven): h words self-validate — phase 0 plain
//   (valid iff != 0xAAAAAAAA ws poison); phase 1 exp-flipped (^0x7F800000).

typedef unsigned int u32;
typedef unsigned long long u64;
typedef u32 u32x4 __attribute__((ext_vector_type(4)));
typedef __attribute__((ext_vector_type(8))) short s16x8;   // 8 bf16 (4 VGPRs)
typedef __attribute__((ext_vector_type(4))) float f32x4;

#define TT 4096
#define HH 512
#define CC 40
#define NG 2048  // 4*H gate rows

__device__ __forceinline__ float sigm(float x) { return 1.0f / (1.0f + __expf(-x)); }
__device__ __forceinline__ float tanh_(float x) { return 1.0f - 2.0f / (__expf(2.0f * x) + 1.0f); }

// system-scope write-through store: lands at MALL (the pollers' read point).
__device__ __forceinline__ void st_sys_u32(u32* p, u32 v) {
    asm volatile("global_store_dword %0, %1, off sc0 sc1"
                 :
                 : "v"(p), "v"(v)
                 : "memory");
}

// 64B system-scope-fresh load (bypass L1+L2, read at MALL) with full wait.
__device__ __forceinline__ void ld_mall_b512(const float* p, u32x4& r0, u32x4& r1,
                                             u32x4& r2, u32x4& r3) {
    asm volatile(
        "global_load_dwordx4 %0, %4, off sc0 sc1\n\t"
        "global_load_dwordx4 %1, %4, off offset:16 sc0 sc1\n\t"
        "global_load_dwordx4 %2, %4, off offset:32 sc0 sc1\n\t"
        "global_load_dwordx4 %3, %4, off offset:48 sc0 sc1\n\t"
        "s_waitcnt vmcnt(0)"
        : "=&v"(r0), "=&v"(r1), "=&v"(r2), "=&v"(r3)
        : "v"(p)
        : "memory");
}

__device__ __forceinline__ bool ok4(const u32x4& v, int phase) {
    if (phase)
        return ((v.x & 0x7F800000u) >= 0x40000000u) &&
               ((v.y & 0x7F800000u) >= 0x40000000u) &&
               ((v.z & 0x7F800000u) >= 0x40000000u) &&
               ((v.w & 0x7F800000u) >= 0x40000000u);
    return (v.x != 0xAAAAAAAAu) && (v.y != 0xAAAAAAAAu) &&
           (v.z != 0xAAAAAAAAu) && (v.w != 0xAAAAAAAAu);
}

// ---------------- split-bf16 MFMA GEMM (pipelined): C = A @ W^T + bias ----------------
// (byte-for-byte r13/r14 — proven)
__device__ __forceinline__ void split_pack8(const float* f, s16x8& hi, s16x8& lo) {
#pragma unroll
    for (int j = 0; j < 8; j++) {
        float x = f[j];
        u32 h = __float_as_uint(x) & 0xFFFF0000u;
        float hf = __uint_as_float(h);
        hi[j] = (short)(h >> 16);
        lo[j] = (short)(__float_as_uint(x - hf) >> 16);
    }
}

__global__ __launch_bounds__(256, 2) void gemm_bf16s_k(const float* __restrict__ A0,
                                                       const float* __restrict__ A1,
                                                       const int* __restrict__ xidx,
                                                       const float* __restrict__ W0,
                                                       const float* __restrict__ bias0,
                                                       float* __restrict__ C0,
                                                       const float* __restrict__ W1,
                                                       const float* __restrict__ bias1,
                                                       float* __restrict__ C1,
                                                       int M, int N, int K, int Ksplit) {
    __shared__ __align__(16) short sAh[128 * 32];
    __shared__ __align__(16) short sAl[128 * 32];
    __shared__ __align__(16) short sWh[128 * 32];
    __shared__ __align__(16) short sWl[128 * 32];
    const int tid = threadIdx.x;
    const int bn = blockIdx.x, bm = blockIdx.y;
    const float* W    = blockIdx.z ? W1 : W0;
    const float* bias = blockIdx.z ? bias1 : bias0;
    float*       C    = blockIdx.z ? C1 : C0;
    const int wid = tid >> 6, lane = tid & 63;
    const int qm = (wid >> 1) * 64, qn = (wid & 1) * 64;  // wave quadrant
    const int fr = lane & 15, fq = lane >> 4;             // frag free idx, k-group

    const int srow = tid >> 1;
    const int kh = (tid & 1) * 16;

    const int am = bm * 128 + srow;
    const float* arow = xidx ? (A0 + (size_t)xidx[am] * K) : nullptr;
    const float* a0r = xidx ? nullptr : (A0 + (size_t)am * Ksplit);
    const float* a1r = xidx ? nullptr : (A1 + (size_t)am * Ksplit);
    const float* wrow = W + (size_t)(bn * 128 + srow) * K;

    f32x4 acc[4][4] = {};

    auto LOADP = [&](int kp, float* fa, float* fw) {
        const int kb = kp * 32 + kh;
        if (kb + 16 <= K) {
#pragma unroll
            for (int j = 0; j < 16; j += 4) {
                int k = kb + j;
                const float* s = xidx ? (arow + k)
                                      : ((k < Ksplit) ? (a0r + k) : (a1r + (k - Ksplit)));
                float4 v = *(const float4*)s;
                fa[j] = v.x; fa[j + 1] = v.y; fa[j + 2] = v.z; fa[j + 3] = v.w;
                float4 wv = *(const float4*)(wrow + k);
                fw[j] = wv.x; fw[j + 1] = wv.y; fw[j + 2] = wv.z; fw[j + 3] = wv.w;
            }
        } else {
#pragma unroll
            for (int j = 0; j < 16; j++) {
                int k = kb + j;
                float av = 0.f, wv = 0.f;
                if (k < K) {
                    av = xidx ? arow[k] : ((k < Ksplit) ? a0r[k] : a1r[k - Ksplit]);
                    wv = wrow[k];
                }
                fa[j] = av; fw[j] = wv;
            }
        }
    };

    float fa[16], fw[16];
    LOADP(0, fa, fw);

    const int NP = (K + 31) >> 5;
    for (int kp = 0; kp < NP; kp++) {
        s16x8 hA[2], lA[2], hW[2], lW[2];
#pragma unroll
        for (int c = 0; c < 2; c++) {
            split_pack8(fa + c * 8, hA[c], lA[c]);
            split_pack8(fw + c * 8, hW[c], lW[c]);
        }
        __syncthreads();
#pragma unroll
        for (int c = 0; c < 2; c++) {
            int ch = (tid & 1) * 2 + c;
            int pch = ch ^ ((srow >> 1) & 3);
            int off = srow * 32 + pch * 8;
            *(s16x8*)&sAh[off] = hA[c];
            *(s16x8*)&sAl[off] = lA[c];
            *(s16x8*)&sWh[off] = hW[c];
            *(s16x8*)&sWl[off] = lW[c];
        }
        __syncthreads();

        if (kp + 1 < NP) LOADP(kp + 1, fa, fw);  // prefetch: hides under MFMA

        s16x8 ah[4], al[4];
#pragma unroll
        for (int m = 0; m < 4; m++) {
            int row = qm + m * 16 + fr;
            int off = row * 32 + ((fq ^ ((row >> 1) & 3)) * 8);
            ah[m] = *(const s16x8*)&sAh[off];
            al[m] = *(const s16x8*)&sAl[off];
        }
#pragma unroll
        for (int n = 0; n < 4; n++) {
            int row = qn + n * 16 + fr;
            int off = row * 32 + ((fq ^ ((row >> 1) & 3)) * 8);
            s16x8 bh = *(const s16x8*)&sWh[off];
            s16x8 bl = *(const s16x8*)&sWl[off];
#pragma unroll
            for (int m = 0; m < 4; m++) {
                acc[m][n] = __builtin_amdgcn_mfma_f32_16x16x32_bf16(ah[m], bh, acc[m][n], 0, 0, 0);
                acc[m][n] = __builtin_amdgcn_mfma_f32_16x16x32_bf16(ah[m], bl, acc[m][n], 0, 0, 0);
                acc[m][n] = __builtin_amdgcn_mfma_f32_16x16x32_bf16(al[m], bh, acc[m][n], 0, 0, 0);
            }
        }
    }

#pragma unroll
    for (int n = 0; n < 4; n++) {
        int gcol = bn * 128 + qn + n * 16 + fr;
        float b = bias[gcol];
#pragma unroll
        for (int m = 0; m < 4; m++) {
            int rbase = bm * 128 + qm + m * 16 + fq * 4;
#pragma unroll
            for (int r2 = 0; r2 < 4; r2++)
                C[(size_t)(rbase + r2) * N + gcol] = acc[m][n][r2] + b;
        }
    }
}

// ---------------- LSTM recurrent phase (r9 structure, r15 64B polls) ----------------
// 64 blocks x 512 threads: dir = blk>>5, wg = blk&31 owns h[wg*16..+16).
// Thread (r=tid>>3, seg=tid&7): gate row grow=(r>>4)*512 + wg*16 + (r&15),
// k in [seg*64,+64). 64 Whh weights/thread in arch VGPRs. Pollers tid<31 spin
// on remote 64B h chunks (= one producer block's coalesced store each) until
// all 16 words pass the phase validity predicate, decode, drop into LDS.
// tid<16 computes gates, stores h (system scope, one coalesced wave-instr)
// and writes own LDS slice.
__global__ __attribute__((amdgpu_flat_work_group_size(512, 512), amdgpu_waves_per_eu(2, 2)))
void lstm_phase_k(const float* __restrict__ WxF,
                  const float* __restrict__ WxB,
                  const float* __restrict__ WhhF,
                  const float* __restrict__ WhhB,
                  float* __restrict__ histF,
                  float* __restrict__ histB,
                  int phase) {
    const int wg = blockIdx.x & 31;
    const int dir = blockIdx.x >> 5;
    const int tid = threadIdx.x;
    const float* Wx = dir ? WxB : WxF;
    const float* Whh = dir ? WhhB : WhhF;
    float* hist = dir ? histB : histF;
    const u32 ENC = phase ? 0x7F800000u : 0u;

    const int r = tid >> 3, seg = tid & 7;
    const int grow = (r >> 4) * 512 + wg * 16 + (r & 15);

    float w[64];
    {
        const float* wr = Whh + (size_t)grow * HH + seg * 64;
#pragma unroll
        for (int i = 0; i < 16; i++) {
            float4 v = *(const float4*)(wr + i * 4);
            w[i * 4 + 0] = v.x; w[i * 4 + 1] = v.y; w[i * 4 + 2] = v.z; w[i * 4 + 3] = v.w;
        }
    }

    // 64B-chunk index this thread polls (32 chunks of 16 floats; skip own wg's)
    const int j = (tid < 31) ? (tid + (tid >= wg ? 1 : 0)) : 0;

    __shared__ float lds_h[8 * 68];  // 8 seg-chunks of 64, stride 68
    __shared__ float lds_g[64];
    float c_state = 0.f;
    int capped = 0;

    for (int s = 0; s < TT; ++s) {
        const int t = dir ? (TT - 1 - s) : s;
        float wxv = 0.f;
        if (seg == 0) wxv = Wx[(size_t)t * NG + grow];  // prefetch, hidden behind poll

        if (s > 0) {
            const int tprev = dir ? (t + 1) : (t - 1);
            if (tid < 31) {
                const float* p = hist + (size_t)tprev * HH + j * 16;
                u32x4 v0, v1, v2, v3;
                if (!capped) {
                    int it = 0;
                    for (;;) {
                        ld_mall_b512(p, v0, v1, v2, v3);
                        if (ok4(v0, phase) && ok4(v1, phase) &&
                            ok4(v2, phase) && ok4(v3, phase)) break;
                        if (++it > (1 << 18)) { capped = 1; break; }  // sticky: never hang
                    }
                } else {
                    ld_mall_b512(p, v0, v1, v2, v3);
                }
                // chunk j covers h[16j..16j+16): row j>>2, cols 16*(j&3)..+16
                float* dst = &lds_h[(j >> 2) * 68 + ((j & 3) * 16)];
                float4 f0, f1, f2, f3;
                f0.x = __uint_as_float(v0.x ^ ENC); f0.y = __uint_as_float(v0.y ^ ENC);
                f0.z = __uint_as_float(v0.z ^ ENC); f0.w = __uint_as_float(v0.w ^ ENC);
                f1.x = __uint_as_float(v1.x ^ ENC); f1.y = __uint_as_float(v1.y ^ ENC);
                f1.z = __uint_as_float(v1.z ^ ENC); f1.w = __uint_as_float(v1.w ^ ENC);
                f2.x = __uint_as_float(v2.x ^ ENC); f2.y = __uint_as_float(v2.y ^ ENC);
                f2.z = __uint_as_float(v2.z ^ ENC); f2.w = __uint_as_float(v2.w ^ ENC);
                f3.x = __uint_as_float(v3.x ^ ENC); f3.y = __uint_as_float(v3.y ^ ENC);
                f3.z = __uint_as_float(v3.z ^ ENC); f3.w = __uint_as_float(v3.w ^ ENC);
                *(float4*)dst       = f0;
                *(float4*)(dst + 4) = f1;
                *(float4*)(dst + 8) = f2;
                *(float4*)(dst + 12)= f3;
            }
            __syncthreads();
            float a0 = 0.f, a1 = 0.f, a2 = 0.f, a3 = 0.f;
            const float4* hv4 = (const float4*)&lds_h[seg * 68];
#pragma unroll
            for (int i = 0; i < 16; i++) {
                float4 hv = hv4[i];
                a0 += w[i * 4 + 0] * hv.x;
                a1 += w[i * 4 + 1] * hv.y;
                a2 += w[i * 4 + 2] * hv.z;
                a3 += w[i * 4 + 3] * hv.w;
            }
            float acc = (a0 + a1) + (a2 + a3);
            acc += __shfl_xor(acc, 1);
            acc += __shfl_xor(acc, 2);
            acc += __shfl_xor(acc, 4);
            if (seg == 0) lds_g[r] = acc + wxv;
        } else {
            if (seg == 0) lds_g[r] = wxv;
        }
        __syncthreads();

        if (tid < 16) {
            float gi = lds_g[tid], gf = lds_g[16 + tid], gg = lds_g[32 + tid], go = lds_g[48 + tid];
            float iv = sigm(gi), fv = sigm(gf), gv = tanh_(gg), ov = sigm(go);
            c_state = fv * c_state + iv * gv;
            float h = ov * tanh_(c_state);
            int hidx = wg * 16 + tid;
            lds_h[(hidx >> 6) * 68 + (hidx & 63)] = h;  // own slice for next step's dot
            st_sys_u32((u32*)&hist[(size_t)t * HH + hidx], __float_as_uint(h) ^ ENC);
        }
        // no end barrier: remote LDS slices are dead until the next poll barrier,
        // and lds_g is rewritten only after that barrier (which waits for tid<16).
    }
}

// ---------------- classifier + log_softmax (writes scores to d_out) ----------------
// hist holds phase-1 encoding: decode = xor 0x7F800000 per word.
__global__ __launch_bounds__(64, 4) void classifier_k(const float* __restrict__ histF,
                                                      const float* __restrict__ histB,
                                                      const float* __restrict__ Wc,
                                                      const float* __restrict__ bc,
                                                      float* __restrict__ outsc) {
    int t = blockIdx.x, lane = threadIdx.x;
    __shared__ float hrow[1024];
    const uint4* hf4 = (const uint4*)(histF + (size_t)t * HH);
    const uint4* hb4 = (const uint4*)(histB + (size_t)t * HH);
#pragma unroll
    for (int jj = 0; jj < 4; jj++) {
        int idx4 = jj * 64 + lane;  // 0..255 uint4s
        uint4 u = (idx4 < 128) ? hf4[idx4] : hb4[idx4 - 128];
        u.x ^= 0x7F800000u; u.y ^= 0x7F800000u; u.z ^= 0x7F800000u; u.w ^= 0x7F800000u;
        float4 v;
        v.x = __uint_as_float(u.x); v.y = __uint_as_float(u.y);
        v.z = __uint_as_float(u.z); v.w = __uint_as_float(u.w);
        *(float4*)&hrow[idx4 * 4] = v;
    }
    __syncthreads();
    float o = 0.f;
    if (lane < CC) {
        o = bc[lane];
        const float4* wr = (const float4*)(Wc + (size_t)lane * 1024);
#pragma unroll 4
        for (int kk = 0; kk < 256; ++kk) {
            float4 w4 = wr[kk];
            float4 h4 = *(const float4*)&hrow[kk * 4];
            o += w4.x * h4.x + w4.y * h4.y + w4.z * h4.z + w4.w * h4.w;
        }
    }
    float m = (lane < CC) ? o : -1e30f;
#pragma unroll
    for (int d = 1; d < 64; d <<= 1) m = fmaxf(m, __shfl_xor(m, d));
    float ex = (lane < CC) ? __expf(o - m) : 0.f;
#pragma unroll
    for (int d = 1; d < 64; d <<= 1) ex += __shfl_xor(ex, d);
    float lse = m + __logf(ex);
    if (lane < CC) outsc[(size_t)t * CC + lane] = o - lse;
}

// ---------------- viterbi stage 1: forward scores only (1 wave, shfl broadcast) ----------------
// s(t) = max_p(s(t-1)[p] + trans[p][next]) + em(t). Candidates via __shfl
// (same values as any broadcast path); fmax TREE is exactly order-independent
// => bit-identical s to the reference scan. No bp here (vit_chunk_k).
__global__ __launch_bounds__(64) void vit_fwd_k(const float* __restrict__ em,
                                                const float* __restrict__ trans,
                                                const float* __restrict__ startv,
                                                const float* __restrict__ endv,
                                                float* __restrict__ s_all,
                                                u32* __restrict__ fi_out) {
    const int lane = threadIdx.x;
    float tcol[CC];
#pragma unroll
    for (int p = 0; p < CC; p++) tcol[p] = (lane < CC) ? trans[p * CC + lane] : -1e30f;
    float s = (lane < CC) ? (startv[lane] + em[lane]) : -1e30f;
    if (lane < CC) s_all[lane] = s;
    float emv = (lane < CC) ? em[(size_t)1 * CC + lane] : 0.f;  // prefetch t=1
    for (int t = 1; t < TT; t++) {
        float c[CC];
#pragma unroll
        for (int p = 0; p < CC; p++) c[p] = __shfl(s, p) + tcol[p];
        float emn = (t + 1 < TT && lane < CC) ? em[(size_t)(t + 1) * CC + lane] : 0.f;
        // exact max tree over 40 (order-independent)
#pragma unroll
        for (int i = 0; i < 20; i++) c[i] = fmaxf(c[i], c[i + 20]);
#pragma unroll
        for (int i = 0; i < 10; i++) c[i] = fmaxf(c[i], c[i + 10]);
#pragma unroll
        for (int i = 0; i < 5; i++) c[i] = fmaxf(c[i], c[i + 5]);
        float m = fmaxf(fmaxf(fmaxf(c[0], c[1]), fmaxf(c[2], c[3])), c[4]);
        s = m + emv;
        emv = emn;
        if (lane < CC) s_all[(size_t)t * CC + lane] = s;
    }
    float fv = (lane < CC) ? (s + endv[lane]) : -1e30f;
    int fi = (lane < CC) ? lane : 63;
#pragma unroll
    for (int d = 1; d < 64; d <<= 1) {
        float ov = __shfl_xor(fv, d);
        int oi = __shfl_xor(fi, d);
        if (ov > fv || (ov == fv && oi < fi)) { fv = ov; fi = oi; }
    }
    if (lane == 0) fi_out[0] = (u32)fi;
}

// ---------------- viterbi stage 2: per-chunk bp + path tables (parallel) ----------------
// (byte-for-byte r14 — proven)
__global__ __launch_bounds__(64) void vit_chunk_k(const float* __restrict__ s_all,
                                                  const float* __restrict__ trans,
                                                  u32* __restrict__ tbl) {
    const int c = blockIdx.x, lane = threadIdx.x;
    const int tlo = c * 16;
    __shared__ float sld[16][CC];          // sld[i] = s(tlo + i - 1)
    __shared__ unsigned char bpl[16][CC];  // bpl[i] = bp[tlo + i]
    for (int idx = lane; idx < 16 * CC; idx += 64) {
        int row = idx / CC, col = idx % CC;
        int t = tlo - 1 + row;
        sld[row][col] = (t >= 0) ? s_all[(size_t)t * CC + col] : 0.f;
    }
    float tcol[CC];
#pragma unroll
    for (int p = 0; p < CC; p++) tcol[p] = (lane < CC) ? trans[p * CC + lane] : 0.f;
    __syncthreads();
    if (lane < CC) {
        for (int i = (c == 0 ? 1 : 0); i < 16; i++) {
            float b = -1e30f; int bi = 0;
#pragma unroll
            for (int p = 0; p < CC; p++) {
                float v = sld[i][p] + tcol[p];
                if (v > b) { b = v; bi = p; }  // strict > = first-max (reference)
            }
            bpl[i][lane] = (unsigned char)bi;
        }
    }
    __syncthreads();
    if (lane < CC) {
        unsigned char pth[16];
        int cur = lane;
        pth[15] = (unsigned char)cur;
        for (int i = 14; i >= 0; i--) { cur = bpl[i + 1][cur]; pth[i] = (unsigned char)cur; }
        u32 entry = (c > 0) ? (u32)bpl[0][cur] : 0u;
        u32* row = tbl + ((size_t)c * CC + lane) * 5;
#pragma unroll
        for (int q = 0; q < 4; q++)
            row[q] = (u32)pth[q * 4] | ((u32)pth[q * 4 + 1] << 8) |
                     ((u32)pth[q * 4 + 2] << 16) | ((u32)pth[q * 4 + 3] << 24);
        row[4] = entry;
    }
}

// ---------------- viterbi stage 3: chunk walk (256 serial lookups) ----------------
__global__ __launch_bounds__(64) void vit_walk_k(const u32* __restrict__ tbl,
                                                 const u32* __restrict__ fi_in,
                                                 float* __restrict__ outtags) {
    if (threadIdx.x != 0) return;
    int cur = (int)fi_in[0];
    for (int c = (TT / 16) - 1; c >= 0; c--) {
        const u32* row = tbl + ((size_t)c * CC + cur) * 5;
        u32 p0 = row[0], p1 = row[1], p2 = row[2], p3 = row[3];
        cur = (int)row[4];
        float* o = outtags + c * 16;
        o[0]  = (float)(p0 & 255); o[1]  = (float)((p0 >> 8) & 255);
        o[2]  = (float)((p0 >> 16) & 255); o[3]  = (float)(p0 >> 24);
        o[4]  = (float)(p1 & 255); o[5]  = (float)((p1 >> 8) & 255);
        o[6]  = (float)((p1 >> 16) & 255); o[7]  = (float)(p1 >> 24);
        o[8]  = (float)(p2 & 255); o[9]  = (float)((p2 >> 8) & 255);
        o[10] = (float)((p2 >> 16) & 255); o[11] = (float)(p2 >> 24);
        o[12] = (float)(p3 & 255); o[13] = (float)((p3 >> 8) & 255);
        o[14] = (float)((p3 >> 16) & 255); o[15] = (float)(p3 >> 24);
    }
}

extern "C" void kernel_launch(void* const* d_in, const int* in_sizes, int n_in,
                              void* d_out, int out_size, void* d_ws, size_t ws_size,
                              hipStream_t stream) {
    const int*   x     = (const int*)d_in[0];
    const float* emb   = (const float*)d_in[1];
    const float* Wih0f = (const float*)d_in[2];
    const float* Whh0f = (const float*)d_in[3];
    const float* b0f   = (const float*)d_in[4];
    const float* Wih0b = (const float*)d_in[5];
    const float* Whh0b = (const float*)d_in[6];
    const float* b0b   = (const float*)d_in[7];
    const float* Wih1f = (const float*)d_in[8];
    const float* Whh1f = (const float*)d_in[9];
    const float* b1f   = (const float*)d_in[10];
    const float* Wih1b = (const float*)d_in[11];
    const float* Whh1b = (const float*)d_in[12];
    const float* b1b   = (const float*)d_in[13];
    const float* Wc    = (const float*)d_in[14];
    const float* bc    = (const float*)d_in[15];
    const float* trans = (const float*)d_in[16];
    const float* startv= (const float*)d_in[17];
    const float* endv  = (const float*)d_in[18];

    char* ws = (char*)d_ws;
    // layout, total 84,148,224 B
    float* WxF  = (float*)(ws + 262144);                   // 4096*2048*4 = 33,554,432
    float* WxB  = (float*)(ws + 33816576);                 // 33,554,432
    float* histF= (float*)(ws + 67371008);                 // 4096*512*4 = 8,388,608
    float* histB= (float*)(ws + 75759616);                 // 8,388,608 -> 84,148,224
    // viterbi scratch reuses the WxF region (dead after lstm phase 1):
    float* s_all = (float*)(ws + 262144);                  // 4096*40*4 = 655,360
    u32*   vtbl  = (u32*)(ws + 262144 + 655360);           // 256*40*5*4 = 204,800
    u32*   fi_ws = (u32*)(ws + 262144 + 655360 + 204800);  // 4 B

    if (ws_size < (size_t)84148224) return;  // diagnostic: zero output => ws too small

    float* out_sc   = (float*)d_out;                 // 4096*40 scores
    float* out_tags = out_sc + (size_t)TT * CC;      // 4096 tags (as float)

    // layer 0 input projections, F+B merged (emb gather fused into GEMM)
    gemm_bf16s_k<<<dim3(16, 32, 2), 256, 0, stream>>>(emb, nullptr, x,
                                                      Wih0f, b0f, WxF, Wih0b, b0b, WxB,
                                                      TT, NG, 300, 300);
    lstm_phase_k<<<64, 512, 0, stream>>>(WxF, WxB, Whh0f, Whh0b, histF, histB, 0);
    // layer 1 input projections, F+B merged (A = concat(histF, histB))
    gemm_bf16s_k<<<dim3(16, 32, 2), 256, 0, stream>>>(histF, histB, nullptr,
                                                      Wih1f, b1f, WxF, Wih1b, b1b, WxB,
                                                      TT, NG, 1024, 512);
    lstm_phase_k<<<64, 512, 0, stream>>>(WxF, WxB, Whh1f, Whh1b, histF, histB, 1);
    classifier_k<<<TT, 64, 0, stream>>>(histF, histB, Wc, bc, out_sc);
    vit_fwd_k<<<1, 64, 0, stream>>>(out_sc, trans, startv, endv, s_all, fi_ws);
    vit_chunk_k<<<TT / 16, 64, 0, stream>>>(s_all, trans, vtbl);
    vit_walk_k<<<1, 64, 0, stream>>>(vtbl, fi_ws, out_tags);
}

// Round 10
// 16622.871 us; speedup vs baseline: 1.1506x; 1.1506x over previous
//
#include <hip/hip_runtime.h>

// BiLSTM-CRF tagger. V=100000 E=300 H=512 C=40 T=4096. ALL I/O float32.
// r16 = best-of recombination (both halves individually proven):
//   - lstm_phase_k: byte-for-byte r14/r9 (32B polls x62, proven 7117us/phase).
//     r15's 64B-poll experiment REGRESSED (+920cy/step): coarser detect
//     quantization (4-load vmcnt(0) drain per iteration) outweighed the
//     halved request rate — contention theory falsified. Poll shape is at
//     its empirical optimum (6 experiments: r7,r8,r9,r11,r15 neg/neutral).
//   - vit_fwd_k: r15's shfl-broadcast version (proven pass, ~0.3-0.4ms faster
//     than r14's LDS version; fmax tree bit-exact, max order-independent).
//   - GEMM/classifier/vit_chunk/vit_walk: byte-for-byte r14.
// Structural note: lstm = 2 phases x 4096 steps x ~1.74us = 14.2ms of
// sequential MALL round trips — the floor of this rendezvous scheme.
// Sync scheme (r4..r9, proven): h words self-validate — phase 0 plain
//   (valid iff != 0xAAAAAAAA ws poison); phase 1 exp-flipped (^0x7F800000).

typedef unsigned int u32;
typedef unsigned long long u64;
typedef u32 u32x4 __attribute__((ext_vector_type(4)));
typedef __attribute__((ext_vector_type(8))) short s16x8;   // 8 bf16 (4 VGPRs)
typedef __attribute__((ext_vector_type(4))) float f32x4;

#define TT 4096
#define HH 512
#define CC 40
#define NG 2048  // 4*H gate rows

__device__ __forceinline__ float sigm(float x) { return 1.0f / (1.0f + __expf(-x)); }
__device__ __forceinline__ float tanh_(float x) { return 1.0f - 2.0f / (__expf(2.0f * x) + 1.0f); }

// system-scope write-through store: lands at MALL (the pollers' read point).
__device__ __forceinline__ void st_sys_u32(u32* p, u32 v) {
    asm volatile("global_store_dword %0, %1, off sc0 sc1"
                 :
                 : "v"(p), "v"(v)
                 : "memory");
}

// 32B system-scope-fresh load (bypass L1+L2, read at MALL).
__device__ __forceinline__ void ld_mall_b256(const float* p, u32x4& r0, u32x4& r1) {
    asm volatile(
        "global_load_dwordx4 %0, %2, off sc0 sc1\n\t"
        "global_load_dwordx4 %1, %2, off offset:16 sc0 sc1\n\t"
        "s_waitcnt vmcnt(0)"
        : "=&v"(r0), "=&v"(r1)
        : "v"(p)
        : "memory");
}

// ---------------- split-bf16 MFMA GEMM (pipelined): C = A @ W^T + bias ----------------
// (byte-for-byte r13/r14 — proven)
__device__ __forceinline__ void split_pack8(const float* f, s16x8& hi, s16x8& lo) {
#pragma unroll
    for (int j = 0; j < 8; j++) {
        float x = f[j];
        u32 h = __float_as_uint(x) & 0xFFFF0000u;
        float hf = __uint_as_float(h);
        hi[j] = (short)(h >> 16);
        lo[j] = (short)(__float_as_uint(x - hf) >> 16);
    }
}

__global__ __launch_bounds__(256, 2) void gemm_bf16s_k(const float* __restrict__ A0,
                                                       const float* __restrict__ A1,
                                                       const int* __restrict__ xidx,
                                                       const float* __restrict__ W0,
                                                       const float* __restrict__ bias0,
                                                       float* __restrict__ C0,
                                                       const float* __restrict__ W1,
                                                       const float* __restrict__ bias1,
                                                       float* __restrict__ C1,
                                                       int M, int N, int K, int Ksplit) {
    __shared__ __align__(16) short sAh[128 * 32];
    __shared__ __align__(16) short sAl[128 * 32];
    __shared__ __align__(16) short sWh[128 * 32];
    __shared__ __align__(16) short sWl[128 * 32];
    const int tid = threadIdx.x;
    const int bn = blockIdx.x, bm = blockIdx.y;
    const float* W    = blockIdx.z ? W1 : W0;
    const float* bias = blockIdx.z ? bias1 : bias0;
    float*       C    = blockIdx.z ? C1 : C0;
    const int wid = tid >> 6, lane = tid & 63;
    const int qm = (wid >> 1) * 64, qn = (wid & 1) * 64;  // wave quadrant
    const int fr = lane & 15, fq = lane >> 4;             // frag free idx, k-group

    const int srow = tid >> 1;
    const int kh = (tid & 1) * 16;

    const int am = bm * 128 + srow;
    const float* arow = xidx ? (A0 + (size_t)xidx[am] * K) : nullptr;
    const float* a0r = xidx ? nullptr : (A0 + (size_t)am * Ksplit);
    const float* a1r = xidx ? nullptr : (A1 + (size_t)am * Ksplit);
    const float* wrow = W + (size_t)(bn * 128 + srow) * K;

    f32x4 acc[4][4] = {};

    auto LOADP = [&](int kp, float* fa, float* fw) {
        const int kb = kp * 32 + kh;
        if (kb + 16 <= K) {
#pragma unroll
            for (int j = 0; j < 16; j += 4) {
                int k = kb + j;
                const float* s = xidx ? (arow + k)
                                      : ((k < Ksplit) ? (a0r + k) : (a1r + (k - Ksplit)));
                float4 v = *(const float4*)s;
                fa[j] = v.x; fa[j + 1] = v.y; fa[j + 2] = v.z; fa[j + 3] = v.w;
                float4 wv = *(const float4*)(wrow + k);
                fw[j] = wv.x; fw[j + 1] = wv.y; fw[j + 2] = wv.z; fw[j + 3] = wv.w;
            }
        } else {
#pragma unroll
            for (int j = 0; j < 16; j++) {
                int k = kb + j;
                float av = 0.f, wv = 0.f;
                if (k < K) {
                    av = xidx ? arow[k] : ((k < Ksplit) ? a0r[k] : a1r[k - Ksplit]);
                    wv = wrow[k];
                }
                fa[j] = av; fw[j] = wv;
            }
        }
    };

    float fa[16], fw[16];
    LOADP(0, fa, fw);

    const int NP = (K + 31) >> 5;
    for (int kp = 0; kp < NP; kp++) {
        s16x8 hA[2], lA[2], hW[2], lW[2];
#pragma unroll
        for (int c = 0; c < 2; c++) {
            split_pack8(fa + c * 8, hA[c], lA[c]);
            split_pack8(fw + c * 8, hW[c], lW[c]);
        }
        __syncthreads();
#pragma unroll
        for (int c = 0; c < 2; c++) {
            int ch = (tid & 1) * 2 + c;
            int pch = ch ^ ((srow >> 1) & 3);
            int off = srow * 32 + pch * 8;
            *(s16x8*)&sAh[off] = hA[c];
            *(s16x8*)&sAl[off] = lA[c];
            *(s16x8*)&sWh[off] = hW[c];
            *(s16x8*)&sWl[off] = lW[c];
        }
        __syncthreads();

        if (kp + 1 < NP) LOADP(kp + 1, fa, fw);  // prefetch: hides under MFMA

        s16x8 ah[4], al[4];
#pragma unroll
        for (int m = 0; m < 4; m++) {
            int row = qm + m * 16 + fr;
            int off = row * 32 + ((fq ^ ((row >> 1) & 3)) * 8);
            ah[m] = *(const s16x8*)&sAh[off];
            al[m] = *(const s16x8*)&sAl[off];
        }
#pragma unroll
        for (int n = 0; n < 4; n++) {
            int row = qn + n * 16 + fr;
            int off = row * 32 + ((fq ^ ((row >> 1) & 3)) * 8);
            s16x8 bh = *(const s16x8*)&sWh[off];
            s16x8 bl = *(const s16x8*)&sWl[off];
#pragma unroll
            for (int m = 0; m < 4; m++) {
                acc[m][n] = __builtin_amdgcn_mfma_f32_16x16x32_bf16(ah[m], bh, acc[m][n], 0, 0, 0);
                acc[m][n] = __builtin_amdgcn_mfma_f32_16x16x32_bf16(ah[m], bl, acc[m][n], 0, 0, 0);
                acc[m][n] = __builtin_amdgcn_mfma_f32_16x16x32_bf16(al[m], bh, acc[m][n], 0, 0, 0);
            }
        }
    }

#pragma unroll
    for (int n = 0; n < 4; n++) {
        int gcol = bn * 128 + qn + n * 16 + fr;
        float b = bias[gcol];
#pragma unroll
        for (int m = 0; m < 4; m++) {
            int rbase = bm * 128 + qm + m * 16 + fq * 4;
#pragma unroll
            for (int r2 = 0; r2 < 4; r2++)
                C[(size_t)(rbase + r2) * N + gcol] = acc[m][n][r2] + b;
        }
    }
}

// ---------------- LSTM recurrent phase (r9/r14, byte-for-byte — proven optimum) ----------------
// 64 blocks x 512 threads: dir = blk>>5, wg = blk&31 owns h[wg*16..+16).
// Thread (r=tid>>3, seg=tid&7): gate row grow=(r>>4)*512 + wg*16 + (r&15),
// k in [seg*64,+64). 64 Whh weights/thread in arch VGPRs. Pollers tid<62 spin on
// remote 32B h chunks (non-atomic sc0 sc1 dwordx4 pairs) until all 8 words pass
// the phase validity predicate, decode, drop into LDS. tid<16 computes gates,
// stores h (system scope write-through, one coalesced wave-instr) and writes
// own LDS slice.
__global__ __attribute__((amdgpu_flat_work_group_size(512, 512), amdgpu_waves_per_eu(2, 2)))
void lstm_phase_k(const float* __restrict__ WxF,
                  const float* __restrict__ WxB,
                  const float* __restrict__ WhhF,
                  const float* __restrict__ WhhB,
                  float* __restrict__ histF,
                  float* __restrict__ histB,
                  int phase) {
    const int wg = blockIdx.x & 31;
    const int dir = blockIdx.x >> 5;
    const int tid = threadIdx.x;
    const float* Wx = dir ? WxB : WxF;
    const float* Whh = dir ? WhhB : WhhF;
    float* hist = dir ? histB : histF;
    const u32 ENC = phase ? 0x7F800000u : 0u;

    const int r = tid >> 3, seg = tid & 7;
    const int grow = (r >> 4) * 512 + wg * 16 + (r & 15);

    float w[64];
    {
        const float* wr = Whh + (size_t)grow * HH + seg * 64;
#pragma unroll
        for (int i = 0; i < 16; i++) {
            float4 v = *(const float4*)(wr + i * 4);
            w[i * 4 + 0] = v.x; w[i * 4 + 1] = v.y; w[i * 4 + 2] = v.z; w[i * 4 + 3] = v.w;
        }
    }

    // 32B-chunk index this thread polls (64 chunks of 8 floats; skip own wg's 2)
    const int j = (tid < 62) ? (tid + (tid >= wg * 2 ? 2 : 0)) : 0;

    __shared__ float lds_h[8 * 68];  // 8 seg-chunks of 64, stride 68
    __shared__ float lds_g[64];
    float c_state = 0.f;
    int capped = 0;

    for (int s = 0; s < TT; ++s) {
        const int t = dir ? (TT - 1 - s) : s;
        float wxv = 0.f;
        if (seg == 0) wxv = Wx[(size_t)t * NG + grow];  // prefetch, hidden behind poll

        if (s > 0) {
            const int tprev = dir ? (t + 1) : (t - 1);
            if (tid < 62) {
                const float* p = hist + (size_t)tprev * HH + j * 8;
                u32x4 v0, v1;
                if (!capped) {
                    int it = 0;
                    for (;;) {
                        ld_mall_b256(p, v0, v1);
                        bool ok;
                        if (phase) {
                            ok = ((v0.x & 0x7F800000u) >= 0x40000000u) &&
                                 ((v0.y & 0x7F800000u) >= 0x40000000u) &&
                                 ((v0.z & 0x7F800000u) >= 0x40000000u) &&
                                 ((v0.w & 0x7F800000u) >= 0x40000000u) &&
                                 ((v1.x & 0x7F800000u) >= 0x40000000u) &&
                                 ((v1.y & 0x7F800000u) >= 0x40000000u) &&
                                 ((v1.z & 0x7F800000u) >= 0x40000000u) &&
                                 ((v1.w & 0x7F800000u) >= 0x40000000u);
                        } else {
                            ok = (v0.x != 0xAAAAAAAAu) && (v0.y != 0xAAAAAAAAu) &&
                                 (v0.z != 0xAAAAAAAAu) && (v0.w != 0xAAAAAAAAu) &&
                                 (v1.x != 0xAAAAAAAAu) && (v1.y != 0xAAAAAAAAu) &&
                                 (v1.z != 0xAAAAAAAAu) && (v1.w != 0xAAAAAAAAu);
                        }
                        if (ok) break;
                        if (++it > (1 << 18)) { capped = 1; break; }  // sticky: never hang
                    }
                } else {
                    ld_mall_b256(p, v0, v1);
                }
                float* dst = &lds_h[(j >> 3) * 68 + ((j & 7) * 8)];
                float4 f0, f1;
                f0.x = __uint_as_float(v0.x ^ ENC); f0.y = __uint_as_float(v0.y ^ ENC);
                f0.z = __uint_as_float(v0.z ^ ENC); f0.w = __uint_as_float(v0.w ^ ENC);
                f1.x = __uint_as_float(v1.x ^ ENC); f1.y = __uint_as_float(v1.y ^ ENC);
                f1.z = __uint_as_float(v1.z ^ ENC); f1.w = __uint_as_float(v1.w ^ ENC);
                *(float4*)dst = f0;
                *(float4*)(dst + 4) = f1;
            }
            __syncthreads();
            float a0 = 0.f, a1 = 0.f, a2 = 0.f, a3 = 0.f;
            const float4* hv4 = (const float4*)&lds_h[seg * 68];
#pragma unroll
            for (int i = 0; i < 16; i++) {
                float4 hv = hv4[i];
                a0 += w[i * 4 + 0] * hv.x;
                a1 += w[i * 4 + 1] * hv.y;
                a2 += w[i * 4 + 2] * hv.z;
                a3 += w[i * 4 + 3] * hv.w;
            }
            float acc = (a0 + a1) + (a2 + a3);
            acc += __shfl_xor(acc, 1);
            acc += __shfl_xor(acc, 2);
            acc += __shfl_xor(acc, 4);
            if (seg == 0) lds_g[r] = acc + wxv;
        } else {
            if (seg == 0) lds_g[r] = wxv;
        }
        __syncthreads();

        if (tid < 16) {
            float gi = lds_g[tid], gf = lds_g[16 + tid], gg = lds_g[32 + tid], go = lds_g[48 + tid];
            float iv = sigm(gi), fv = sigm(gf), gv = tanh_(gg), ov = sigm(go);
            c_state = fv * c_state + iv * gv;
            float h = ov * tanh_(c_state);
            int hidx = wg * 16 + tid;
            lds_h[(hidx >> 6) * 68 + (hidx & 63)] = h;  // own slice for next step's dot
            st_sys_u32((u32*)&hist[(size_t)t * HH + hidx], __float_as_uint(h) ^ ENC);
        }
        // no end barrier: remote LDS slices are dead until the next poll barrier,
        // and lds_g is rewritten only after that barrier (which waits for tid<16).
    }
}

// ---------------- classifier + log_softmax (writes scores to d_out) ----------------
// hist holds phase-1 encoding: decode = xor 0x7F800000 per word.
__global__ __launch_bounds__(64, 4) void classifier_k(const float* __restrict__ histF,
                                                      const float* __restrict__ histB,
                                                      const float* __restrict__ Wc,
                                                      const float* __restrict__ bc,
                                                      float* __restrict__ outsc) {
    int t = blockIdx.x, lane = threadIdx.x;
    __shared__ float hrow[1024];
    const uint4* hf4 = (const uint4*)(histF + (size_t)t * HH);
    const uint4* hb4 = (const uint4*)(histB + (size_t)t * HH);
#pragma unroll
    for (int jj = 0; jj < 4; jj++) {
        int idx4 = jj * 64 + lane;  // 0..255 uint4s
        uint4 u = (idx4 < 128) ? hf4[idx4] : hb4[idx4 - 128];
        u.x ^= 0x7F800000u; u.y ^= 0x7F800000u; u.z ^= 0x7F800000u; u.w ^= 0x7F800000u;
        float4 v;
        v.x = __uint_as_float(u.x); v.y = __uint_as_float(u.y);
        v.z = __uint_as_float(u.z); v.w = __uint_as_float(u.w);
        *(float4*)&hrow[idx4 * 4] = v;
    }
    __syncthreads();
    float o = 0.f;
    if (lane < CC) {
        o = bc[lane];
        const float4* wr = (const float4*)(Wc + (size_t)lane * 1024);
#pragma unroll 4
        for (int kk = 0; kk < 256; ++kk) {
            float4 w4 = wr[kk];
            float4 h4 = *(const float4*)&hrow[kk * 4];
            o += w4.x * h4.x + w4.y * h4.y + w4.z * h4.z + w4.w * h4.w;
        }
    }
    float m = (lane < CC) ? o : -1e30f;
#pragma unroll
    for (int d = 1; d < 64; d <<= 1) m = fmaxf(m, __shfl_xor(m, d));
    float ex = (lane < CC) ? __expf(o - m) : 0.f;
#pragma unroll
    for (int d = 1; d < 64; d <<= 1) ex += __shfl_xor(ex, d);
    float lse = m + __logf(ex);
    if (lane < CC) outsc[(size_t)t * CC + lane] = o - lse;
}

// ---------------- viterbi stage 1: forward scores only (1 wave, shfl broadcast) ----------------
// (r15-proven) s(t) = max_p(s(t-1)[p] + trans[p][next]) + em(t). Candidates
// via __shfl; fmax TREE is exactly order-independent => bit-identical s to
// the reference scan. No bp here (vit_chunk_k recomputes it in parallel).
__global__ __launch_bounds__(64) void vit_fwd_k(const float* __restrict__ em,
                                                const float* __restrict__ trans,
                                                const float* __restrict__ startv,
                                                const float* __restrict__ endv,
                                                float* __restrict__ s_all,
                                                u32* __restrict__ fi_out) {
    const int lane = threadIdx.x;
    float tcol[CC];
#pragma unroll
    for (int p = 0; p < CC; p++) tcol[p] = (lane < CC) ? trans[p * CC + lane] : -1e30f;
    float s = (lane < CC) ? (startv[lane] + em[lane]) : -1e30f;
    if (lane < CC) s_all[lane] = s;
    float emv = (lane < CC) ? em[(size_t)1 * CC + lane] : 0.f;  // prefetch t=1
    for (int t = 1; t < TT; t++) {
        float c[CC];
#pragma unroll
        for (int p = 0; p < CC; p++) c[p] = __shfl(s, p) + tcol[p];
        float emn = (t + 1 < TT && lane < CC) ? em[(size_t)(t + 1) * CC + lane] : 0.f;
        // exact max tree over 40 (order-independent)
#pragma unroll
        for (int i = 0; i < 20; i++) c[i] = fmaxf(c[i], c[i + 20]);
#pragma unroll
        for (int i = 0; i < 10; i++) c[i] = fmaxf(c[i], c[i + 10]);
#pragma unroll
        for (int i = 0; i < 5; i++) c[i] = fmaxf(c[i], c[i + 5]);
        float m = fmaxf(fmaxf(fmaxf(c[0], c[1]), fmaxf(c[2], c[3])), c[4]);
        s = m + emv;
        emv = emn;
        if (lane < CC) s_all[(size_t)t * CC + lane] = s;
    }
    float fv = (lane < CC) ? (s + endv[lane]) : -1e30f;
    int fi = (lane < CC) ? lane : 63;
#pragma unroll
    for (int d = 1; d < 64; d <<= 1) {
        float ov = __shfl_xor(fv, d);
        int oi = __shfl_xor(fi, d);
        if (ov > fv || (ov == fv && oi < fi)) { fv = ov; fi = oi; }
    }
    if (lane == 0) fi_out[0] = (u32)fi;
}

// ---------------- viterbi stage 2: per-chunk bp + path tables (parallel) ----------------
// (byte-for-byte r14 — proven)
__global__ __launch_bounds__(64) void vit_chunk_k(const float* __restrict__ s_all,
                                                  const float* __restrict__ trans,
                                                  u32* __restrict__ tbl) {
    const int c = blockIdx.x, lane = threadIdx.x;
    const int tlo = c * 16;
    __shared__ float sld[16][CC];          // sld[i] = s(tlo + i - 1)
    __shared__ unsigned char bpl[16][CC];  // bpl[i] = bp[tlo + i]
    for (int idx = lane; idx < 16 * CC; idx += 64) {
        int row = idx / CC, col = idx % CC;
        int t = tlo - 1 + row;
        sld[row][col] = (t >= 0) ? s_all[(size_t)t * CC + col] : 0.f;
    }
    float tcol[CC];
#pragma unroll
    for (int p = 0; p < CC; p++) tcol[p] = (lane < CC) ? trans[p * CC + lane] : 0.f;
    __syncthreads();
    if (lane < CC) {
        for (int i = (c == 0 ? 1 : 0); i < 16; i++) {
            float b = -1e30f; int bi = 0;
#pragma unroll
            for (int p = 0; p < CC; p++) {
                float v = sld[i][p] + tcol[p];
                if (v > b) { b = v; bi = p; }  // strict > = first-max (reference)
            }
            bpl[i][lane] = (unsigned char)bi;
        }
    }
    __syncthreads();
    if (lane < CC) {
        unsigned char pth[16];
        int cur = lane;
        pth[15] = (unsigned char)cur;
        for (int i = 14; i >= 0; i--) { cur = bpl[i + 1][cur]; pth[i] = (unsigned char)cur; }
        u32 entry = (c > 0) ? (u32)bpl[0][cur] : 0u;
        u32* row = tbl + ((size_t)c * CC + lane) * 5;
#pragma unroll
        for (int q = 0; q < 4; q++)
            row[q] = (u32)pth[q * 4] | ((u32)pth[q * 4 + 1] << 8) |
                     ((u32)pth[q * 4 + 2] << 16) | ((u32)pth[q * 4 + 3] << 24);
        row[4] = entry;
    }
}

// ---------------- viterbi stage 3: chunk walk (256 serial lookups) ----------------
__global__ __launch_bounds__(64) void vit_walk_k(const u32* __restrict__ tbl,
                                                 const u32* __restrict__ fi_in,
                                                 float* __restrict__ outtags) {
    if (threadIdx.x != 0) return;
    int cur = (int)fi_in[0];
    for (int c = (TT / 16) - 1; c >= 0; c--) {
        const u32* row = tbl + ((size_t)c * CC + cur) * 5;
        u32 p0 = row[0], p1 = row[1], p2 = row[2], p3 = row[3];
        cur = (int)row[4];
        float* o = outtags + c * 16;
        o[0]  = (float)(p0 & 255); o[1]  = (float)((p0 >> 8) & 255);
        o[2]  = (float)((p0 >> 16) & 255); o[3]  = (float)(p0 >> 24);
        o[4]  = (float)(p1 & 255); o[5]  = (float)((p1 >> 8) & 255);
        o[6]  = (float)((p1 >> 16) & 255); o[7]  = (float)(p1 >> 24);
        o[8]  = (float)(p2 & 255); o[9]  = (float)((p2 >> 8) & 255);
        o[10] = (float)((p2 >> 16) & 255); o[11] = (float)(p2 >> 24);
        o[12] = (float)(p3 & 255); o[13] = (float)((p3 >> 8) & 255);
        o[14] = (float)((p3 >> 16) & 255); o[15] = (float)(p3 >> 24);
    }
}

extern "C" void kernel_launch(void* const* d_in, const int* in_sizes, int n_in,
                              void* d_out, int out_size, void* d_ws, size_t ws_size,
                              hipStream_t stream) {
    const int*   x     = (const int*)d_in[0];
    const float* emb   = (const float*)d_in[1];
    const float* Wih0f = (const float*)d_in[2];
    const float* Whh0f = (const float*)d_in[3];
    const float* b0f   = (const float*)d_in[4];
    const float* Wih0b = (const float*)d_in[5];
    const float* Whh0b = (const float*)d_in[6];
    const float* b0b   = (const float*)d_in[7];
    const float* Wih1f = (const float*)d_in[8];
    const float* Whh1f = (const float*)d_in[9];
    const float* b1f   = (const float*)d_in[10];
    const float* Wih1b = (const float*)d_in[11];
    const float* Whh1b = (const float*)d_in[12];
    const float* b1b   = (const float*)d_in[13];
    const float* Wc    = (const float*)d_in[14];
    const float* bc    = (const float*)d_in[15];
    const float* trans = (const float*)d_in[16];
    const float* startv= (const float*)d_in[17];
    const float* endv  = (const float*)d_in[18];

    char* ws = (char*)d_ws;
    // layout, total 84,148,224 B
    float* WxF  = (float*)(ws + 262144);                   // 4096*2048*4 = 33,554,432
    float* WxB  = (float*)(ws + 33816576);                 // 33,554,432
    float* histF= (float*)(ws + 67371008);                 // 4096*512*4 = 8,388,608
    float* histB= (float*)(ws + 75759616);                 // 8,388,608 -> 84,148,224
    // viterbi scratch reuses the WxF region (dead after lstm phase 1):
    float* s_all = (float*)(ws + 262144);                  // 4096*40*4 = 655,360
    u32*   vtbl  = (u32*)(ws + 262144 + 655360);           // 256*40*5*4 = 204,800
    u32*   fi_ws = (u32*)(ws + 262144 + 655360 + 204800);  // 4 B

    if (ws_size < (size_t)84148224) return;  // diagnostic: zero output => ws too small

    float* out_sc   = (float*)d_out;                 // 4096*40 scores
    float* out_tags = out_sc + (size_t)TT * CC;      // 4096 tags (as float)

    // layer 0 input projections, F+B merged (emb gather fused into GEMM)
    gemm_bf16s_k<<<dim3(16, 32, 2), 256, 0, stream>>>(emb, nullptr, x,
                                                      Wih0f, b0f, WxF, Wih0b, b0b, WxB,
                                                      TT, NG, 300, 300);
    lstm_phase_k<<<64, 512, 0, stream>>>(WxF, WxB, Whh0f, Whh0b, histF, histB, 0);
    // layer 1 input projections, F+B merged (A = concat(histF, histB))
    gemm_bf16s_k<<<dim3(16, 32, 2), 256, 0, stream>>>(histF, histB, nullptr,
                                                      Wih1f, b1f, WxF, Wih1b, b1b, WxB,
                                                      TT, NG, 1024, 512);
    lstm_phase_k<<<64, 512, 0, stream>>>(WxF, WxB, Whh1f, Whh1b, histF, histB, 1);
    classifier_k<<<TT, 64, 0, stream>>>(histF, histB, Wc, bc, out_sc);
    vit_fwd_k<<<1, 64, 0, stream>>>(out_sc, trans, startv, endv, s_all, fi_ws);
    vit_chunk_k<<<TT / 16, 64, 0, stream>>>(s_all, trans, vtbl);
    vit_walk_k<<<1, 64, 0, stream>>>(vtbl, fi_ws, out_tags);
}